// Round 2
// baseline (5389.972 us; speedup 1.0000x reference)
//
#include <hip/hip_runtime.h>
#include <hip/hip_bf16.h>
#include <math.h>

#define HIDN 256
#define GATES 1024
#define BB 8
#define LLEN 128
#define WLEN 48
#define SNUM 5
#define PLEN 32
#define NSEQ 1024
#define EMBD 256

__device__ __forceinline__ float sigf(float x){ return 1.0f/(1.0f+expf(-x)); }

// =======================================================================
// Generalized tiled GEMM: C(MxN) = op(A)(MxK) @ B(NxK)^T [+bias] [relu]
// 64x64 tile, 256 threads, transposed LDS for b128 fragment reads.
// GATHER: A row m -> A[gidx[m]] (lda=K). SPLIT: K=512, k<256 from A, k>=256
// from A2 (both lda=256). ostride: output row stride in elements.
// =======================================================================
template<bool GATHER, bool BIAS, bool RELU, bool SPLIT>
__global__ __launch_bounds__(256) void gemm_abt64_k(
  const float* __restrict__ A, const float* __restrict__ A2,
  const float* __restrict__ Bm, const float* __restrict__ bias,
  float* __restrict__ C, const int* __restrict__ gidx,
  int K, int N, int ostride)
{
  __shared__ float As[32][68];
  __shared__ float Bs[32][68];
  const int tid = threadIdx.x;
  const int m0 = blockIdx.x*64, n0 = blockIdx.y*64;
  const int tx = tid & 15, ty = tid >> 4;
  const int lr = tid >> 3;
  const int lc = (tid & 7) * 4;
  float acc[4][4] = {};
  for (int k0 = 0; k0 < K; k0 += 32){
    #pragma unroll
    for (int hf = 0; hf < 2; ++hf){
      const int r = lr + hf*32;
      int am = m0 + r;
      if (GATHER) am = gidx[am];
      const float* asrc;
      if (SPLIT){
        if (k0 < 256) asrc = A  + (size_t)am*256 + k0 + lc;
        else          asrc = A2 + (size_t)am*256 + (k0-256) + lc;
      } else {
        asrc = A + (size_t)am*K + k0 + lc;
      }
      float4 av = *reinterpret_cast<const float4*>(asrc);
      float4 bv = *reinterpret_cast<const float4*>(Bm + (size_t)(n0+r)*K + k0 + lc);
      As[lc+0][r]=av.x; As[lc+1][r]=av.y; As[lc+2][r]=av.z; As[lc+3][r]=av.w;
      Bs[lc+0][r]=bv.x; Bs[lc+1][r]=bv.y; Bs[lc+2][r]=bv.z; Bs[lc+3][r]=bv.w;
    }
    __syncthreads();
    #pragma unroll
    for (int kk = 0; kk < 32; ++kk){
      const float4 a = *reinterpret_cast<const float4*>(&As[kk][ty*4]);
      const float4 b = *reinterpret_cast<const float4*>(&Bs[kk][tx*4]);
      acc[0][0] += a.x*b.x; acc[0][1] += a.x*b.y; acc[0][2] += a.x*b.z; acc[0][3] += a.x*b.w;
      acc[1][0] += a.y*b.x; acc[1][1] += a.y*b.y; acc[1][2] += a.y*b.z; acc[1][3] += a.y*b.w;
      acc[2][0] += a.z*b.x; acc[2][1] += a.z*b.y; acc[2][2] += a.z*b.z; acc[2][3] += a.z*b.w;
      acc[3][0] += a.w*b.x; acc[3][1] += a.w*b.y; acc[3][2] += a.w*b.z; acc[3][3] += a.w*b.w;
    }
    __syncthreads();
  }
  float4 bb;
  if (BIAS) bb = *reinterpret_cast<const float4*>(bias + n0 + tx*4);
  else      { bb.x=0.f; bb.y=0.f; bb.z=0.f; bb.w=0.f; }
  #pragma unroll
  for (int i = 0; i < 4; ++i){
    float4 o;
    o.x = acc[i][0]+bb.x; o.y = acc[i][1]+bb.y; o.z = acc[i][2]+bb.z; o.w = acc[i][3]+bb.w;
    if (RELU){ o.x=fmaxf(o.x,0.f); o.y=fmaxf(o.y,0.f); o.z=fmaxf(o.z,0.f); o.w=fmaxf(o.w,0.f); }
    *reinterpret_cast<float4*>(C + (size_t)(m0+ty*4+i)*ostride + n0 + tx*4) = o;
  }
}

// =======================================================================
// Fallback word LSTM gates (K=512: emb-gather x-part + h-part), as round 1
// =======================================================================
__global__ __launch_bounds__(256) void word_gates_k(
    const int* __restrict__ tok, const float* __restrict__ emb,
    const float* __restrict__ Wih, const float* __restrict__ Whh,
    const float* __restrict__ bias, const float* __restrict__ hbuf,
    float* __restrict__ G, int t)
{
  __shared__ float As[32][68];
  __shared__ float Bs[32][68];
  const int tid = threadIdx.x;
  const int m0 = blockIdx.x*64, n0 = blockIdx.y*64;
  const int tx = tid & 15, ty = tid >> 4;
  const int lr = tid >> 3;
  const int lc = (tid & 7) * 4;
  float acc[4][4] = {};
  for (int kt = 0; kt < 16; ++kt){
    const int k0 = (kt & 7)*32;
    const bool xp = (kt < 8);
    #pragma unroll
    for (int hf = 0; hf < 2; ++hf){
      const int r = lr + hf*32;
      float4 av, bv;
      if (xp){
        const int token = tok[(m0+r)*WLEN + t];
        av = *reinterpret_cast<const float4*>(emb + (size_t)token*EMBD + k0 + lc);
      } else {
        av = *reinterpret_cast<const float4*>(hbuf + (size_t)(m0+r)*HIDN + k0 + lc);
      }
      const float* bptr = (xp ? Wih : Whh) + (size_t)(n0+r)*HIDN + k0 + lc;
      bv = *reinterpret_cast<const float4*>(bptr);
      As[lc+0][r]=av.x; As[lc+1][r]=av.y; As[lc+2][r]=av.z; As[lc+3][r]=av.w;
      Bs[lc+0][r]=bv.x; Bs[lc+1][r]=bv.y; Bs[lc+2][r]=bv.z; Bs[lc+3][r]=bv.w;
    }
    __syncthreads();
    #pragma unroll
    for (int kk = 0; kk < 32; ++kk){
      const float4 a = *reinterpret_cast<const float4*>(&As[kk][ty*4]);
      const float4 b = *reinterpret_cast<const float4*>(&Bs[kk][tx*4]);
      acc[0][0] += a.x*b.x; acc[0][1] += a.x*b.y; acc[0][2] += a.x*b.z; acc[0][3] += a.x*b.w;
      acc[1][0] += a.y*b.x; acc[1][1] += a.y*b.y; acc[1][2] += a.y*b.z; acc[1][3] += a.y*b.w;
      acc[2][0] += a.z*b.x; acc[2][1] += a.z*b.y; acc[2][2] += a.z*b.z; acc[2][3] += a.z*b.w;
      acc[3][0] += a.w*b.x; acc[3][1] += a.w*b.y; acc[3][2] += a.w*b.z; acc[3][3] += a.w*b.w;
    }
    __syncthreads();
  }
  const float4 bb = *reinterpret_cast<const float4*>(bias + n0 + tx*4);
  #pragma unroll
  for (int i = 0; i < 4; ++i){
    float4 o;
    o.x = acc[i][0]+bb.x; o.y = acc[i][1]+bb.y; o.z = acc[i][2]+bb.z; o.w = acc[i][3]+bb.w;
    *reinterpret_cast<float4*>(G + (size_t)(m0+ty*4+i)*GATES + n0 + tx*4) = o;
  }
}

// fallback elementwise update (G already has x-part + bias)
__global__ __launch_bounds__(256) void word_update_k(
  const float* __restrict__ G, float* __restrict__ h, float* __restrict__ c,
  float* __restrict__ wout, int t)
{
  int idx = blockIdx.x*256 + threadIdx.x;
  int m = idx >> 8, j = idx & 255;
  const float* g = G + (size_t)m*GATES;
  float gi = g[j], gf = g[HIDN+j], gg = g[2*HIDN+j], go = g[3*HIDN+j];
  float cc = c[idx];
  cc = sigf(gf)*cc + sigf(gi)*tanhf(gg);
  float hh = sigf(go)*tanhf(cc);
  c[idx] = cc; h[idx] = hh;
  wout[(size_t)m*WLEN*HIDN + (size_t)t*HIDN + j] = hh;
}

// update when x-part precomputed in X: gate = G(h-part) + X(x-part incl bias)
__global__ __launch_bounds__(256) void word_update2_k(
  const float* __restrict__ G, const float* __restrict__ X,
  float* __restrict__ h, float* __restrict__ c,
  float* __restrict__ wout, int t)
{
  const int m = blockIdx.x, j = threadIdx.x;
  const int idx = m*HIDN + j;
  const float* g = G + (size_t)m*GATES;
  const float* x = X + ((size_t)m*WLEN + t)*GATES;
  float gi = g[j]        + x[j];
  float gf = g[HIDN+j]   + x[HIDN+j];
  float gg = g[2*HIDN+j] + x[2*HIDN+j];
  float go = g[3*HIDN+j] + x[3*HIDN+j];
  float cc = c[idx];
  cc = sigf(gf)*cc + sigf(gi)*tanhf(gg);
  float hh = sigf(go)*tanhf(cc);
  c[idx] = cc; h[idx] = hh;
  wout[((size_t)m*WLEN + t)*HIDN + j] = hh;
}

// =======================================================================
// attention logits (fused tanh + ws2 contraction)
// =======================================================================
__global__ __launch_bounds__(256) void att_logits_k(
  const float* __restrict__ wout, const float* __restrict__ ws1,
  const float* __restrict__ ws2, float* __restrict__ logits)
{
  __shared__ float As[64][33];
  __shared__ float Bs[256][33];
  __shared__ float red[64][16];
  const int tid = threadIdx.x;
  const int m0 = blockIdx.x*64;
  const int tx = tid & 15, ty = tid >> 4;
  const int lr = tid >> 3;
  const int lc = (tid & 7) * 4;
  float acc[4][16] = {};
  for (int k0 = 0; k0 < 256; k0 += 32){
    #pragma unroll
    for (int hf = 0; hf < 2; ++hf){
      const int r = lr + hf*32;
      float4 av = *reinterpret_cast<const float4*>(wout + (size_t)(m0+r)*HIDN + k0 + lc);
      As[r][lc+0]=av.x; As[r][lc+1]=av.y; As[r][lc+2]=av.z; As[r][lc+3]=av.w;
    }
    #pragma unroll
    for (int h8 = 0; h8 < 8; ++h8){
      const int r = lr + h8*32;
      float4 bv = *reinterpret_cast<const float4*>(ws1 + (size_t)r*HIDN + k0 + lc);
      Bs[r][lc+0]=bv.x; Bs[r][lc+1]=bv.y; Bs[r][lc+2]=bv.z; Bs[r][lc+3]=bv.w;
    }
    __syncthreads();
    for (int kk = 0; kk < 32; ++kk){
      float a0 = As[ty*4+0][kk], a1 = As[ty*4+1][kk], a2 = As[ty*4+2][kk], a3 = As[ty*4+3][kk];
      #pragma unroll
      for (int u = 0; u < 16; ++u){
        float b = Bs[tx + 16*u][kk];
        acc[0][u] += a0*b; acc[1][u] += a1*b; acc[2][u] += a2*b; acc[3][u] += a3*b;
      }
    }
    __syncthreads();
  }
  float p0=0, p1=0, p2=0, p3=0;
  #pragma unroll
  for (int u = 0; u < 16; ++u){
    float w2 = ws2[tx + 16*u];
    p0 += w2*tanhf(acc[0][u]);
    p1 += w2*tanhf(acc[1][u]);
    p2 += w2*tanhf(acc[2][u]);
    p3 += w2*tanhf(acc[3][u]);
  }
  red[ty*4+0][tx] = p0; red[ty*4+1][tx] = p1; red[ty*4+2][tx] = p2; red[ty*4+3][tx] = p3;
  __syncthreads();
  if (tid < 64){
    float s = 0;
    #pragma unroll
    for (int q = 0; q < 16; ++q) s += red[tid][q];
    logits[m0 + tid] = s;
  }
}

__global__ __launch_bounds__(256) void att_softmax_k(
  const float* __restrict__ wout, const float* __restrict__ logits,
  const int* __restrict__ tok, float* __restrict__ att)
{
  __shared__ float e[WLEN];
  __shared__ float den_s;
  const int n = blockIdx.x, j = threadIdx.x;
  if (j < WLEN){
    float l = logits[n*WLEN + j];
    if (tok[n*WLEN + j] == 0) l -= 10000.0f;
    e[j] = l;
  }
  __syncthreads();
  if (j == 0){
    float mx = -1e30f;
    for (int w = 0; w < WLEN; ++w) mx = fmaxf(mx, e[w]);
    float den = 0.f;
    for (int w = 0; w < WLEN; ++w){ float ee = expf(e[w]-mx); e[w] = ee; den += ee; }
    den_s = den;
  }
  __syncthreads();
  const float inv = 1.0f/den_s;
  float a = 0.f;
  for (int w = 0; w < WLEN; ++w)
    a += e[w]*wout[((size_t)n*WLEN + w)*HIDN + j];
  att[(size_t)n*HIDN + j] = a*inv;
}

// =======================================================================
// Fused conv+sess recurrent LSTM, register-resident Whh.
// blocks 0..7: conv (T=128); blocks 8..39: sess (T=32).
// thread n holds Whh[n][0:256] in 64 float4 regs; h broadcast via LDS.
// =======================================================================
__global__ __launch_bounds__(1024) void recur_reg_k(
  const float* __restrict__ xwc, const float* __restrict__ cWhh, float* __restrict__ convb,
  const float* __restrict__ xws, const float* __restrict__ sWhh, float* __restrict__ soutb)
{
  const float* xw; const float* W; float* out; int seq, T;
  if (blockIdx.x < 8){ seq = blockIdx.x;     T = 128; xw = xwc; W = cWhh; out = convb; }
  else               { seq = blockIdx.x - 8; T = 32;  xw = xws; W = sWhh; out = soutb; }
  __shared__ float h_s[HIDN];
  __shared__ float g_s[GATES];
  const int tid = threadIdx.x;
  float4 w[64];
  const float4* wr = reinterpret_cast<const float4*>(W + (size_t)tid*HIDN);
  #pragma unroll
  for (int k = 0; k < 64; ++k) w[k] = wr[k];
  float c_reg = 0.f;
  if (tid < HIDN) h_s[tid] = 0.f;
  __syncthreads();
  const float4* h4 = reinterpret_cast<const float4*>(h_s);
  for (int t = 0; t < T; ++t){
    float acc = xw[(size_t)(seq*T + t)*GATES + tid];
    float a0=0.f, a1=0.f, a2=0.f, a3=0.f;
    #pragma unroll
    for (int k = 0; k < 64; k += 4){
      float4 h0 = h4[k+0], h1 = h4[k+1], h2 = h4[k+2], h3 = h4[k+3];
      a0 += w[k+0].x*h0.x + w[k+0].y*h0.y + w[k+0].z*h0.z + w[k+0].w*h0.w;
      a1 += w[k+1].x*h1.x + w[k+1].y*h1.y + w[k+1].z*h1.z + w[k+1].w*h1.w;
      a2 += w[k+2].x*h2.x + w[k+2].y*h2.y + w[k+2].z*h2.z + w[k+2].w*h2.w;
      a3 += w[k+3].x*h3.x + w[k+3].y*h3.y + w[k+3].z*h3.z + w[k+3].w*h3.w;
    }
    g_s[tid] = acc + (a0+a1) + (a2+a3);
    __syncthreads();
    if (tid < HIDN){
      float gi = g_s[tid], gf = g_s[HIDN+tid], gg = g_s[2*HIDN+tid], go = g_s[3*HIDN+tid];
      float cc = sigf(gf)*c_reg + sigf(gi)*tanhf(gg);
      c_reg = cc;
      float hh = sigf(go)*tanhf(cc);
      h_s[tid] = hh;
      out[(size_t)(seq*T + t)*HIDN + tid] = hh;
    }
    __syncthreads();
  }
}

// =======================================================================
// Parallel "scan": the carry only reaches back one step and carries a pure
// function of stm/sess_out, so everything parallelizes over (b,l).
// Writes state rows s=1..4 and the [one_res | conv_shift] GEMM input.
// =======================================================================
__global__ __launch_bounds__(256) void scan_prep_k(
  const float* __restrict__ sess_out, const float* __restrict__ conv_out,
  const int* __restrict__ stm, float* __restrict__ state, float* __restrict__ onec)
{
  const int bl = blockIdx.x;
  const int b = bl >> 7, l = bl & 127;
  const int j = threadIdx.x;
  float ones = 0.f;
  #pragma unroll
  for (int s = 1; s < SNUM; ++s){
    const int sv = stm[(size_t)bl*SNUM + s];
    float vg = 0.f;
    if (sv > 0){
      int p = sv - 1; if (p > PLEN-1) p = PLEN-1;
      vg = sess_out[((size_t)(b*4 + (s-1))*PLEN + p)*HIDN + j];
    }
    float v = vg;
    if (sv == -1){
      v = 0.f;
      if (l > 0){
        const int pv = stm[(size_t)(bl-1)*SNUM + s];
        if (pv > 0){
          int p2 = pv - 1; if (p2 > PLEN-1) p2 = PLEN-1;
          v = sess_out[((size_t)(b*4 + (s-1))*PLEN + p2)*HIDN + j];
        }
      }
    }
    if (sv != 0) ones += v;
    state[((size_t)bl*SNUM + s)*HIDN + j] = vg;
  }
  onec[(size_t)bl*(2*HIDN) + j] = ones * 0.25f;
  const int lp = (l == 0) ? 0 : (l-1);
  onec[(size_t)bl*(2*HIDN) + HIDN + j] = conv_out[((size_t)(b*LLEN + lp))*HIDN + j];
}

// =======================================================================
// final scores + log_softmax (up precomputed by GEMM)
// =======================================================================
__global__ __launch_bounds__(256) void scores_k(
  const float* __restrict__ state, const float* __restrict__ up, float* __restrict__ out)
{
  const int n = blockIdx.x, j = threadIdx.x;
  __shared__ float red[SNUM][4];
  const float u = up[(size_t)n*HIDN + j];
  const int lane = j & 63, wid = j >> 6;
  #pragma unroll
  for (int s = 0; s < SNUM; ++s){
    float p = state[((size_t)n*SNUM + s)*HIDN + j]*u;
    for (int off = 32; off; off >>= 1) p += __shfl_down(p, off, 64);
    if (lane == 0) red[s][wid] = p;
  }
  __syncthreads();
  if (j == 0){
    float sc[SNUM]; float mx = -1e30f;
    #pragma unroll
    for (int s = 0; s < SNUM; ++s){
      sc[s] = red[s][0]+red[s][1]+red[s][2]+red[s][3];
      mx = fmaxf(mx, sc[s]);
    }
    float den = 0.f;
    #pragma unroll
    for (int s = 0; s < SNUM; ++s) den += expf(sc[s]-mx);
    const float ls = logf(den);
    #pragma unroll
    for (int s = 0; s < SNUM; ++s) out[(size_t)n*SNUM + s] = sc[s]-mx-ls;
  }
}

// ---------------- workspace layout (float offsets) ----------------
static const size_t OFF_WOUT  = 0;                         // 49152*256
static const size_t OFF_G     = 12582912;                  // 1024*1024
static const size_t OFF_H     = OFF_G     + 1048576;       // 1024*256
static const size_t OFF_C     = OFF_H     + 262144;
static const size_t OFF_ATT   = OFF_C     + 262144;
static const size_t OFF_XWC   = OFF_ATT   + 262144;        // 1024*1024
static const size_t OFF_XWS   = OFF_XWC   + 1048576;
static const size_t OFF_CONV  = OFF_XWS   + 1048576;       // 1024*256
static const size_t OFF_SOUT  = OFF_CONV  + 262144;        // 32*32*256
static const size_t OFF_STATE = OFF_SOUT  + 262144;        // 1024*5*256
static const size_t OFF_ONEC  = OFF_STATE + 1310720;       // 1024*512
static const size_t OFF_UP    = OFF_ONEC  + 524288;        // 1024*256
static const size_t OFF_LOG   = OFF_UP    + 262144;        // 49152
static const size_t OFF_X     = OFF_LOG   + 49152;         // 49152*1024 (optional)
static const size_t NEED_X_FLOATS = OFF_X + (size_t)49152*1024;

extern "C" void kernel_launch(void* const* d_in, const int* in_sizes, int n_in,
                              void* d_out, int out_size, void* d_ws, size_t ws_size,
                              hipStream_t stream)
{
  const int*   tok   = (const int*)  d_in[0];
  const int*   perm  = (const int*)  d_in[2];
  const int*   stm   = (const int*)  d_in[3];
  const float* emb   = (const float*)d_in[5];
  const float* uWih  = (const float*)d_in[6];
  const float* uWhh  = (const float*)d_in[7];
  const float* ub    = (const float*)d_in[8];
  const float* ws1   = (const float*)d_in[9];
  const float* ws2   = (const float*)d_in[10];
  const float* cWih  = (const float*)d_in[11];
  const float* cWhh  = (const float*)d_in[12];
  const float* cb    = (const float*)d_in[13];
  const float* sWih  = (const float*)d_in[14];
  const float* sWhh  = (const float*)d_in[15];
  const float* sb    = (const float*)d_in[16];
  const float* Wp    = (const float*)d_in[17];
  const float* bp    = (const float*)d_in[18];
  const float* Ws    = (const float*)d_in[19];
  const float* bs    = (const float*)d_in[20];

  float* wsf    = (float*)d_ws;
  float* wout   = wsf + OFF_WOUT;
  float* G      = wsf + OFF_G;
  float* h      = wsf + OFF_H;
  float* c      = wsf + OFF_C;
  float* att    = wsf + OFF_ATT;
  float* xwc    = wsf + OFF_XWC;
  float* xws    = wsf + OFF_XWS;
  float* convb  = wsf + OFF_CONV;
  float* soutb  = wsf + OFF_SOUT;
  float* statem = wsf + OFF_STATE;
  float* onec   = wsf + OFF_ONEC;
  float* upb    = wsf + OFF_UP;
  float* logits = wsf + OFF_LOG;
  float* X      = wsf + OFF_X;

  const bool useX = ws_size >= NEED_X_FLOATS*sizeof(float);

  // zero h, c (contiguous)
  hipMemsetAsync(h, 0, 2*262144*sizeof(float), stream);

  // ---- word LSTM ----
  if (useX){
    // X = emb[tok] @ Wih^T + b for all 49152 (seq,t) rows, one big GEMM
    gemm_abt64_k<true,true,false,false><<<dim3(768,16), 256, 0, stream>>>(
      emb, nullptr, uWih, ub, X, tok, 256, GATES, GATES);
    for (int t = 0; t < WLEN; ++t){
      gemm_abt64_k<false,false,false,false><<<dim3(16,16), 256, 0, stream>>>(
        h, nullptr, uWhh, nullptr, G, nullptr, 256, GATES, GATES);
      word_update2_k<<<1024, 256, 0, stream>>>(G, X, h, c, wout, t);
    }
  } else {
    for (int t = 0; t < WLEN; ++t){
      word_gates_k<<<dim3(16,16), 256, 0, stream>>>(tok, emb, uWih, uWhh, ub, h, G, t);
      word_update_k<<<1024, 256, 0, stream>>>(G, h, c, wout, t);
    }
  }

  // ---- attention ----
  att_logits_k<<<768, 256, 0, stream>>>(wout, ws1, ws2, logits);
  att_softmax_k<<<1024, 256, 0, stream>>>(wout, logits, tok, att);

  // ---- x-parts of conv/session LSTMs (bias folded) ----
  gemm_abt64_k<false,true,false,false><<<dim3(16,16), 256, 0, stream>>>(
    att, nullptr, cWih, cb, xwc, nullptr, 256, GATES, GATES);
  gemm_abt64_k<true,true,false,false><<<dim3(16,16), 256, 0, stream>>>(
    att, nullptr, sWih, sb, xws, perm, 256, GATES, GATES);

  // ---- fused recurrent LSTMs (register-resident weights) ----
  recur_reg_k<<<40, 1024, 0, stream>>>(xwc, cWhh, convb, xws, sWhh, soutb);

  // ---- parallel state "scan" ----
  scan_prep_k<<<1024, 256, 0, stream>>>(soutb, convb, stm, statem, onec);
  // state[:,:,0,:] = relu([one_res|conv_shift] @ Wp^T + bp), strided output
  gemm_abt64_k<false,true,true,false><<<dim3(16,4), 256, 0, stream>>>(
    onec, nullptr, Wp, bp, statem, nullptr, 512, HIDN, SNUM*HIDN);

  // ---- final projection + scores + log_softmax ----
  gemm_abt64_k<false,true,true,true><<<dim3(16,4), 256, 0, stream>>>(
    att, convb, Ws, bs, upb, nullptr, 512, HIDN, HIDN);
  scores_k<<<1024, 256, 0, stream>>>(statem, upb, (float*)d_out);
}

// Round 3
// 2206.093 us; speedup vs baseline: 2.4432x; 2.4432x over previous
//
#include <hip/hip_runtime.h>
#include <hip/hip_bf16.h>
#include <math.h>

#define HIDN 256
#define GATES 1024
#define BB 8
#define LLEN 128
#define WLEN 48
#define SNUM 5
#define PLEN 32
#define NSEQ 1024
#define EMBD 256

typedef _Float16 f16;
typedef _Float16 h2_t __attribute__((ext_vector_type(2)));

__device__ __forceinline__ float sigf(float x){ return 1.0f/(1.0f+expf(-x)); }

__device__ __forceinline__ float fd2(unsigned int w, unsigned int h, float acc){
  h2_t wa = __builtin_bit_cast(h2_t, w);
  h2_t hb = __builtin_bit_cast(h2_t, h);
#if defined(__has_builtin)
#if __has_builtin(__builtin_amdgcn_fdot2)
  return __builtin_amdgcn_fdot2(wa, hb, acc, false);
#else
  return acc + (float)wa[0]*(float)hb[0] + (float)wa[1]*(float)hb[1];
#endif
#else
  return acc + (float)wa[0]*(float)hb[0] + (float)wa[1]*(float)hb[1];
#endif
}

__device__ __forceinline__ float dot8(uint4 w, uint4 h, float acc){
  acc = fd2(w.x, h.x, acc);
  acc = fd2(w.y, h.y, acc);
  acc = fd2(w.z, h.z, acc);
  acc = fd2(w.w, h.w, acc);
  return acc;
}

// =======================================================================
// Generalized tiled GEMM: C(MxN) = op(A)(MxK) @ B(NxK)^T [+bias] [relu]
// =======================================================================
template<bool GATHER, bool BIAS, bool RELU, bool SPLIT>
__global__ __launch_bounds__(256) void gemm_abt64_k(
  const float* __restrict__ A, const float* __restrict__ A2,
  const float* __restrict__ Bm, const float* __restrict__ bias,
  float* __restrict__ C, const int* __restrict__ gidx,
  int K, int N, int ostride)
{
  __shared__ float As[32][68];
  __shared__ float Bs[32][68];
  const int tid = threadIdx.x;
  const int m0 = blockIdx.x*64, n0 = blockIdx.y*64;
  const int tx = tid & 15, ty = tid >> 4;
  const int lr = tid >> 3;
  const int lc = (tid & 7) * 4;
  float acc[4][4] = {};
  for (int k0 = 0; k0 < K; k0 += 32){
    #pragma unroll
    for (int hf = 0; hf < 2; ++hf){
      const int r = lr + hf*32;
      int am = m0 + r;
      if (GATHER) am = gidx[am];
      const float* asrc;
      if (SPLIT){
        if (k0 < 256) asrc = A  + (size_t)am*256 + k0 + lc;
        else          asrc = A2 + (size_t)am*256 + (k0-256) + lc;
      } else {
        asrc = A + (size_t)am*K + k0 + lc;
      }
      float4 av = *reinterpret_cast<const float4*>(asrc);
      float4 bv = *reinterpret_cast<const float4*>(Bm + (size_t)(n0+r)*K + k0 + lc);
      As[lc+0][r]=av.x; As[lc+1][r]=av.y; As[lc+2][r]=av.z; As[lc+3][r]=av.w;
      Bs[lc+0][r]=bv.x; Bs[lc+1][r]=bv.y; Bs[lc+2][r]=bv.z; Bs[lc+3][r]=bv.w;
    }
    __syncthreads();
    #pragma unroll
    for (int kk = 0; kk < 32; ++kk){
      const float4 a = *reinterpret_cast<const float4*>(&As[kk][ty*4]);
      const float4 b = *reinterpret_cast<const float4*>(&Bs[kk][tx*4]);
      acc[0][0] += a.x*b.x; acc[0][1] += a.x*b.y; acc[0][2] += a.x*b.z; acc[0][3] += a.x*b.w;
      acc[1][0] += a.y*b.x; acc[1][1] += a.y*b.y; acc[1][2] += a.y*b.z; acc[1][3] += a.y*b.w;
      acc[2][0] += a.z*b.x; acc[2][1] += a.z*b.y; acc[2][2] += a.z*b.z; acc[2][3] += a.z*b.w;
      acc[3][0] += a.w*b.x; acc[3][1] += a.w*b.y; acc[3][2] += a.w*b.z; acc[3][3] += a.w*b.w;
    }
    __syncthreads();
  }
  float4 bb;
  if (BIAS) bb = *reinterpret_cast<const float4*>(bias + n0 + tx*4);
  else      { bb.x=0.f; bb.y=0.f; bb.z=0.f; bb.w=0.f; }
  #pragma unroll
  for (int i = 0; i < 4; ++i){
    float4 o;
    o.x = acc[i][0]+bb.x; o.y = acc[i][1]+bb.y; o.z = acc[i][2]+bb.z; o.w = acc[i][3]+bb.w;
    if (RELU){ o.x=fmaxf(o.x,0.f); o.y=fmaxf(o.y,0.f); o.z=fmaxf(o.z,0.f); o.w=fmaxf(o.w,0.f); }
    *reinterpret_cast<float4*>(C + (size_t)(m0+ty*4+i)*ostride + n0 + tx*4) = o;
  }
}

// =======================================================================
// Fallback word LSTM gates (K=512), as round 1
// =======================================================================
__global__ __launch_bounds__(256) void word_gates_k(
    const int* __restrict__ tok, const float* __restrict__ emb,
    const float* __restrict__ Wih, const float* __restrict__ Whh,
    const float* __restrict__ bias, const float* __restrict__ hbuf,
    float* __restrict__ G, int t)
{
  __shared__ float As[32][68];
  __shared__ float Bs[32][68];
  const int tid = threadIdx.x;
  const int m0 = blockIdx.x*64, n0 = blockIdx.y*64;
  const int tx = tid & 15, ty = tid >> 4;
  const int lr = tid >> 3;
  const int lc = (tid & 7) * 4;
  float acc[4][4] = {};
  for (int kt = 0; kt < 16; ++kt){
    const int k0 = (kt & 7)*32;
    const bool xp = (kt < 8);
    #pragma unroll
    for (int hf = 0; hf < 2; ++hf){
      const int r = lr + hf*32;
      float4 av, bv;
      if (xp){
        const int token = tok[(m0+r)*WLEN + t];
        av = *reinterpret_cast<const float4*>(emb + (size_t)token*EMBD + k0 + lc);
      } else {
        av = *reinterpret_cast<const float4*>(hbuf + (size_t)(m0+r)*HIDN + k0 + lc);
      }
      const float* bptr = (xp ? Wih : Whh) + (size_t)(n0+r)*HIDN + k0 + lc;
      bv = *reinterpret_cast<const float4*>(bptr);
      As[lc+0][r]=av.x; As[lc+1][r]=av.y; As[lc+2][r]=av.z; As[lc+3][r]=av.w;
      Bs[lc+0][r]=bv.x; Bs[lc+1][r]=bv.y; Bs[lc+2][r]=bv.z; Bs[lc+3][r]=bv.w;
    }
    __syncthreads();
    #pragma unroll
    for (int kk = 0; kk < 32; ++kk){
      const float4 a = *reinterpret_cast<const float4*>(&As[kk][ty*4]);
      const float4 b = *reinterpret_cast<const float4*>(&Bs[kk][tx*4]);
      acc[0][0] += a.x*b.x; acc[0][1] += a.x*b.y; acc[0][2] += a.x*b.z; acc[0][3] += a.x*b.w;
      acc[1][0] += a.y*b.x; acc[1][1] += a.y*b.y; acc[1][2] += a.y*b.z; acc[1][3] += a.y*b.w;
      acc[2][0] += a.z*b.x; acc[2][1] += a.z*b.y; acc[2][2] += a.z*b.z; acc[2][3] += a.z*b.w;
      acc[3][0] += a.w*b.x; acc[3][1] += a.w*b.y; acc[3][2] += a.w*b.z; acc[3][3] += a.w*b.w;
    }
    __syncthreads();
  }
  const float4 bb = *reinterpret_cast<const float4*>(bias + n0 + tx*4);
  #pragma unroll
  for (int i = 0; i < 4; ++i){
    float4 o;
    o.x = acc[i][0]+bb.x; o.y = acc[i][1]+bb.y; o.z = acc[i][2]+bb.z; o.w = acc[i][3]+bb.w;
    *reinterpret_cast<float4*>(G + (size_t)(m0+ty*4+i)*GATES + n0 + tx*4) = o;
  }
}

__global__ __launch_bounds__(256) void word_update_k(
  const float* __restrict__ G, float* __restrict__ h, float* __restrict__ c,
  float* __restrict__ wout, int t)
{
  int idx = blockIdx.x*256 + threadIdx.x;
  int m = idx >> 8, j = idx & 255;
  const float* g = G + (size_t)m*GATES;
  float gi = g[j], gf = g[HIDN+j], gg = g[2*HIDN+j], go = g[3*HIDN+j];
  float cc = c[idx];
  cc = sigf(gf)*cc + sigf(gi)*tanhf(gg);
  float hh = sigf(go)*tanhf(cc);
  c[idx] = cc; h[idx] = hh;
  wout[(size_t)m*WLEN*HIDN + (size_t)t*HIDN + j] = hh;
}

__global__ __launch_bounds__(256) void word_update2_k(
  const float* __restrict__ G, const float* __restrict__ X,
  float* __restrict__ h, float* __restrict__ c,
  float* __restrict__ wout, int t)
{
  const int m = blockIdx.x, j = threadIdx.x;
  const int idx = m*HIDN + j;
  const float* g = G + (size_t)m*GATES;
  const float* x = X + ((size_t)m*WLEN + t)*GATES;
  float gi = g[j]        + x[j];
  float gf = g[HIDN+j]   + x[HIDN+j];
  float gg = g[2*HIDN+j] + x[2*HIDN+j];
  float go = g[3*HIDN+j] + x[3*HIDN+j];
  float cc = c[idx];
  cc = sigf(gf)*cc + sigf(gi)*tanhf(gg);
  float hh = sigf(go)*tanhf(cc);
  c[idx] = cc; h[idx] = hh;
  wout[((size_t)m*WLEN + t)*HIDN + j] = hh;
}

// =======================================================================
// attention logits (fused tanh + ws2 contraction)
// =======================================================================
__global__ __launch_bounds__(256) void att_logits_k(
  const float* __restrict__ wout, const float* __restrict__ ws1,
  const float* __restrict__ ws2, float* __restrict__ logits)
{
  __shared__ float As[64][33];
  __shared__ float Bs[256][33];
  __shared__ float red[64][16];
  const int tid = threadIdx.x;
  const int m0 = blockIdx.x*64;
  const int tx = tid & 15, ty = tid >> 4;
  const int lr = tid >> 3;
  const int lc = (tid & 7) * 4;
  float acc[4][16] = {};
  for (int k0 = 0; k0 < 256; k0 += 32){
    #pragma unroll
    for (int hf = 0; hf < 2; ++hf){
      const int r = lr + hf*32;
      float4 av = *reinterpret_cast<const float4*>(wout + (size_t)(m0+r)*HIDN + k0 + lc);
      As[r][lc+0]=av.x; As[r][lc+1]=av.y; As[r][lc+2]=av.z; As[r][lc+3]=av.w;
    }
    #pragma unroll
    for (int h8 = 0; h8 < 8; ++h8){
      const int r = lr + h8*32;
      float4 bv = *reinterpret_cast<const float4*>(ws1 + (size_t)r*HIDN + k0 + lc);
      Bs[r][lc+0]=bv.x; Bs[r][lc+1]=bv.y; Bs[r][lc+2]=bv.z; Bs[r][lc+3]=bv.w;
    }
    __syncthreads();
    for (int kk = 0; kk < 32; ++kk){
      float a0 = As[ty*4+0][kk], a1 = As[ty*4+1][kk], a2 = As[ty*4+2][kk], a3 = As[ty*4+3][kk];
      #pragma unroll
      for (int u = 0; u < 16; ++u){
        float b = Bs[tx + 16*u][kk];
        acc[0][u] += a0*b; acc[1][u] += a1*b; acc[2][u] += a2*b; acc[3][u] += a3*b;
      }
    }
    __syncthreads();
  }
  float p0=0, p1=0, p2=0, p3=0;
  #pragma unroll
  for (int u = 0; u < 16; ++u){
    float w2 = ws2[tx + 16*u];
    p0 += w2*tanhf(acc[0][u]);
    p1 += w2*tanhf(acc[1][u]);
    p2 += w2*tanhf(acc[2][u]);
    p3 += w2*tanhf(acc[3][u]);
  }
  red[ty*4+0][tx] = p0; red[ty*4+1][tx] = p1; red[ty*4+2][tx] = p2; red[ty*4+3][tx] = p3;
  __syncthreads();
  if (tid < 64){
    float s = 0;
    #pragma unroll
    for (int q = 0; q < 16; ++q) s += red[tid][q];
    logits[m0 + tid] = s;
  }
}

__global__ __launch_bounds__(256) void att_softmax_k(
  const float* __restrict__ wout, const float* __restrict__ logits,
  const int* __restrict__ tok, float* __restrict__ att)
{
  __shared__ float e[WLEN];
  __shared__ float den_s;
  const int n = blockIdx.x, j = threadIdx.x;
  if (j < WLEN){
    float l = logits[n*WLEN + j];
    if (tok[n*WLEN + j] == 0) l -= 10000.0f;
    e[j] = l;
  }
  __syncthreads();
  if (j == 0){
    float mx = -1e30f;
    for (int w = 0; w < WLEN; ++w) mx = fmaxf(mx, e[w]);
    float den = 0.f;
    for (int w = 0; w < WLEN; ++w){ float ee = expf(e[w]-mx); e[w] = ee; den += ee; }
    den_s = den;
  }
  __syncthreads();
  const float inv = 1.0f/den_s;
  float a = 0.f;
  for (int w = 0; w < WLEN; ++w)
    a += e[w]*wout[((size_t)n*WLEN + w)*HIDN + j];
  att[(size_t)n*HIDN + j] = a*inv;
}

// =======================================================================
// fp32 -> f16 weight conversion (both recurrent weight matrices)
// =======================================================================
__global__ __launch_bounds__(256) void cvt_w16_k(
  const float* __restrict__ a, const float* __restrict__ b,
  f16* __restrict__ oa, f16* __restrict__ ob)
{
  const int i = blockIdx.x*256 + threadIdx.x;   // 0..262143
  oa[i] = (f16)a[i];
  ob[i] = (f16)b[i];
}

// =======================================================================
// Fused conv+sess recurrent LSTM. 512 threads/block, 2 gate rows/thread.
// Weights f16: k=0..191 in 192 VGPRs (packed pairs), k=192..255 in 128 KB
// dynamic LDS ([chunk][row] 16B units -> stride-1-by-lane ds_read_b128).
// h kept in LDS as f16 (broadcast reads). blocks 0..7: conv (T=128);
// blocks 8..39: sess (T=32).
// =======================================================================
__global__ __launch_bounds__(512, 2) void recur512_k(
  const float* __restrict__ xwc, const f16* __restrict__ w16c, float* __restrict__ convb,
  const float* __restrict__ xws, const f16* __restrict__ w16s, float* __restrict__ soutb)
{
  const float* xw; const f16* w16; float* out; int seq, T;
  if (blockIdx.x < 8){ seq = blockIdx.x;     T = 128; xw = xwc; w16 = w16c; out = convb; }
  else               { seq = blockIdx.x - 8; T = 32;  xw = xws; w16 = w16s; out = soutb; }

  extern __shared__ char smem[];
  uint4* w_lds  = (uint4*)smem;                       // 8*1024 units = 128 KB
  float* g_s    = (float*)(smem + 131072);            // 1024 floats = 4 KB
  f16*   h_half = (f16*)(smem + 131072 + 4096);       // 256 halves = 512 B
  const uint4* h4 = (const uint4*)h_half;             // 32 units

  const int tid = threadIdx.x;
  const int n0 = tid, n1 = tid + 512;

  // stage LDS weight tail (k=192..255) for both owned rows
  #pragma unroll
  for (int cth = 0; cth < 8; ++cth){
    w_lds[cth*1024 + n0] = *reinterpret_cast<const uint4*>(w16 + (size_t)n0*HIDN + 192 + cth*8);
    w_lds[cth*1024 + n1] = *reinterpret_cast<const uint4*>(w16 + (size_t)n1*HIDN + 192 + cth*8);
  }
  // register weights (k=0..191): 24 uint4 per row = 192 VGPRs total
  uint4 wr0[24], wr1[24];
  #pragma unroll
  for (int cth = 0; cth < 24; ++cth){
    wr0[cth] = *reinterpret_cast<const uint4*>(w16 + (size_t)n0*HIDN + cth*8);
    wr1[cth] = *reinterpret_cast<const uint4*>(w16 + (size_t)n1*HIDN + cth*8);
  }
  if (tid < 128) reinterpret_cast<uint4*>(h_half)[tid >> 2] = uint4{0,0,0,0};
  float c_reg = 0.f;
  __syncthreads();

  for (int t = 0; t < T; ++t){
    const size_t gbase = (size_t)(seq*T + t)*GATES;
    float acc0 = xw[gbase + n0];
    float acc1 = xw[gbase + n1];
    #pragma unroll
    for (int cth = 0; cth < 24; ++cth){
      const uint4 hv = h4[cth];
      acc0 = dot8(wr0[cth], hv, acc0);
      acc1 = dot8(wr1[cth], hv, acc1);
    }
    #pragma unroll
    for (int cth = 0; cth < 8; ++cth){
      const uint4 hv = h4[24 + cth];
      const uint4 w0 = w_lds[cth*1024 + n0];
      const uint4 w1 = w_lds[cth*1024 + n1];
      acc0 = dot8(w0, hv, acc0);
      acc1 = dot8(w1, hv, acc1);
    }
    g_s[n0] = acc0;
    g_s[n1] = acc1;
    __syncthreads();
    if (tid < HIDN){
      const int j = tid;
      float gi = g_s[j], gf = g_s[HIDN+j], gg = g_s[2*HIDN+j], go = g_s[3*HIDN+j];
      float cc = sigf(gf)*c_reg + sigf(gi)*tanhf(gg);
      c_reg = cc;
      float hh = sigf(go)*tanhf(cc);
      h_half[j] = (f16)hh;
      out[(size_t)(seq*T + t)*HIDN + j] = hh;
    }
    __syncthreads();
  }
}

// =======================================================================
// Parallel state "scan" prep (carry reaches back exactly one step)
// =======================================================================
__global__ __launch_bounds__(256) void scan_prep_k(
  const float* __restrict__ sess_out, const float* __restrict__ conv_out,
  const int* __restrict__ stm, float* __restrict__ state, float* __restrict__ onec)
{
  const int bl = blockIdx.x;
  const int b = bl >> 7, l = bl & 127;
  const int j = threadIdx.x;
  float ones = 0.f;
  #pragma unroll
  for (int s = 1; s < SNUM; ++s){
    const int sv = stm[(size_t)bl*SNUM + s];
    float vg = 0.f;
    if (sv > 0){
      int p = sv - 1; if (p > PLEN-1) p = PLEN-1;
      vg = sess_out[((size_t)(b*4 + (s-1))*PLEN + p)*HIDN + j];
    }
    float v = vg;
    if (sv == -1){
      v = 0.f;
      if (l > 0){
        const int pv = stm[(size_t)(bl-1)*SNUM + s];
        if (pv > 0){
          int p2 = pv - 1; if (p2 > PLEN-1) p2 = PLEN-1;
          v = sess_out[((size_t)(b*4 + (s-1))*PLEN + p2)*HIDN + j];
        }
      }
    }
    if (sv != 0) ones += v;
    state[((size_t)bl*SNUM + s)*HIDN + j] = vg;
  }
  onec[(size_t)bl*(2*HIDN) + j] = ones * 0.25f;
  const int lp = (l == 0) ? 0 : (l-1);
  onec[(size_t)bl*(2*HIDN) + HIDN + j] = conv_out[((size_t)(b*LLEN + lp))*HIDN + j];
}

// =======================================================================
// final scores + log_softmax
// =======================================================================
__global__ __launch_bounds__(256) void scores_k(
  const float* __restrict__ state, const float* __restrict__ up, float* __restrict__ out)
{
  const int n = blockIdx.x, j = threadIdx.x;
  __shared__ float red[SNUM][4];
  const float u = up[(size_t)n*HIDN + j];
  const int lane = j & 63, wid = j >> 6;
  #pragma unroll
  for (int s = 0; s < SNUM; ++s){
    float p = state[((size_t)n*SNUM + s)*HIDN + j]*u;
    for (int off = 32; off; off >>= 1) p += __shfl_down(p, off, 64);
    if (lane == 0) red[s][wid] = p;
  }
  __syncthreads();
  if (j == 0){
    float sc[SNUM]; float mx = -1e30f;
    #pragma unroll
    for (int s = 0; s < SNUM; ++s){
      sc[s] = red[s][0]+red[s][1]+red[s][2]+red[s][3];
      mx = fmaxf(mx, sc[s]);
    }
    float den = 0.f;
    #pragma unroll
    for (int s = 0; s < SNUM; ++s) den += expf(sc[s]-mx);
    const float ls = logf(den);
    #pragma unroll
    for (int s = 0; s < SNUM; ++s) out[(size_t)n*SNUM + s] = sc[s]-mx-ls;
  }
}

// ---------------- workspace layout (float offsets) ----------------
static const size_t OFF_WOUT  = 0;                         // 49152*256
static const size_t OFF_G     = 12582912;                  // 1024*1024
static const size_t OFF_H     = OFF_G     + 1048576;
static const size_t OFF_C     = OFF_H     + 262144;
static const size_t OFF_ATT   = OFF_C     + 262144;
static const size_t OFF_XWC   = OFF_ATT   + 262144;
static const size_t OFF_XWS   = OFF_XWC   + 1048576;
static const size_t OFF_CONV  = OFF_XWS   + 1048576;
static const size_t OFF_SOUT  = OFF_CONV  + 262144;
static const size_t OFF_STATE = OFF_SOUT  + 262144;        // 1024*5*256
static const size_t OFF_ONEC  = OFF_STATE + 1310720;       // 1024*512
static const size_t OFF_UP    = OFF_ONEC  + 524288;
static const size_t OFF_LOG   = OFF_UP    + 262144;        // 49152
static const size_t OFF_W16C  = OFF_LOG   + 49152;         // 1024*256 f16 = 131072 floats
static const size_t OFF_W16S  = OFF_W16C  + 131072;
static const size_t OFF_X     = OFF_W16S  + 131072;        // 49152*1024 (optional)
static const size_t NEED_X_FLOATS = OFF_X + (size_t)49152*1024;

static const size_t RECUR_LDS_BYTES = 131072 + 4096 + 512; // 135680

extern "C" void kernel_launch(void* const* d_in, const int* in_sizes, int n_in,
                              void* d_out, int out_size, void* d_ws, size_t ws_size,
                              hipStream_t stream)
{
  const int*   tok   = (const int*)  d_in[0];
  const int*   perm  = (const int*)  d_in[2];
  const int*   stm   = (const int*)  d_in[3];
  const float* emb   = (const float*)d_in[5];
  const float* uWih  = (const float*)d_in[6];
  const float* uWhh  = (const float*)d_in[7];
  const float* ub    = (const float*)d_in[8];
  const float* ws1   = (const float*)d_in[9];
  const float* ws2   = (const float*)d_in[10];
  const float* cWih  = (const float*)d_in[11];
  const float* cWhh  = (const float*)d_in[12];
  const float* cb    = (const float*)d_in[13];
  const float* sWih  = (const float*)d_in[14];
  const float* sWhh  = (const float*)d_in[15];
  const float* sb    = (const float*)d_in[16];
  const float* Wp    = (const float*)d_in[17];
  const float* bp    = (const float*)d_in[18];
  const float* Ws    = (const float*)d_in[19];
  const float* bs    = (const float*)d_in[20];

  float* wsf    = (float*)d_ws;
  float* wout   = wsf + OFF_WOUT;
  float* G      = wsf + OFF_G;
  float* h      = wsf + OFF_H;
  float* c      = wsf + OFF_C;
  float* att    = wsf + OFF_ATT;
  float* xwc    = wsf + OFF_XWC;
  float* xws    = wsf + OFF_XWS;
  float* convb  = wsf + OFF_CONV;
  float* soutb  = wsf + OFF_SOUT;
  float* statem = wsf + OFF_STATE;
  float* onec   = wsf + OFF_ONEC;
  float* upb    = wsf + OFF_UP;
  float* logits = wsf + OFF_LOG;
  f16*   w16c   = (f16*)(wsf + OFF_W16C);
  f16*   w16s   = (f16*)(wsf + OFF_W16S);
  float* X      = wsf + OFF_X;

  const bool useX = ws_size >= NEED_X_FLOATS*sizeof(float);

  // allow >64KB dynamic LDS for the recurrent kernel (idempotent, host-side)
  hipFuncSetAttribute(reinterpret_cast<const void*>(recur512_k),
                      hipFuncAttributeMaxDynamicSharedMemorySize,
                      (int)RECUR_LDS_BYTES);

  // zero h, c (contiguous)
  hipMemsetAsync(h, 0, 2*262144*sizeof(float), stream);

  // recurrent weights -> f16 (one-time per call)
  cvt_w16_k<<<1024, 256, 0, stream>>>(cWhh, sWhh, w16c, w16s);

  // ---- word LSTM ----
  if (useX){
    gemm_abt64_k<true,true,false,false><<<dim3(768,16), 256, 0, stream>>>(
      emb, nullptr, uWih, ub, X, tok, 256, GATES, GATES);
    for (int t = 0; t < WLEN; ++t){
      gemm_abt64_k<false,false,false,false><<<dim3(16,16), 256, 0, stream>>>(
        h, nullptr, uWhh, nullptr, G, nullptr, 256, GATES, GATES);
      word_update2_k<<<1024, 256, 0, stream>>>(G, X, h, c, wout, t);
    }
  } else {
    for (int t = 0; t < WLEN; ++t){
      word_gates_k<<<dim3(16,16), 256, 0, stream>>>(tok, emb, uWih, uWhh, ub, h, G, t);
      word_update_k<<<1024, 256, 0, stream>>>(G, h, c, wout, t);
    }
  }

  // ---- attention ----
  att_logits_k<<<768, 256, 0, stream>>>(wout, ws1, ws2, logits);
  att_softmax_k<<<1024, 256, 0, stream>>>(wout, logits, tok, att);

  // ---- x-parts of conv/session LSTMs (bias folded) ----
  gemm_abt64_k<false,true,false,false><<<dim3(16,16), 256, 0, stream>>>(
    att, nullptr, cWih, cb, xwc, nullptr, 256, GATES, GATES);
  gemm_abt64_k<true,true,false,false><<<dim3(16,16), 256, 0, stream>>>(
    att, nullptr, sWih, sb, xws, perm, 256, GATES, GATES);

  // ---- fused recurrent LSTMs (f16 reg+LDS resident weights) ----
  recur512_k<<<40, 512, RECUR_LDS_BYTES, stream>>>(xwc, w16c, convb, xws, w16s, soutb);

  // ---- parallel state "scan" ----
  scan_prep_k<<<1024, 256, 0, stream>>>(soutb, convb, stm, statem, onec);
  gemm_abt64_k<false,true,true,false><<<dim3(16,4), 256, 0, stream>>>(
    onec, nullptr, Wp, bp, statem, nullptr, 512, HIDN, SNUM*HIDN);

  // ---- final projection + scores + log_softmax ----
  gemm_abt64_k<false,true,true,true><<<dim3(16,4), 256, 0, stream>>>(
    att, convb, Ws, bs, upb, nullptr, 512, HIDN, HIDN);
  scores_k<<<1024, 256, 0, stream>>>(statem, upb, (float*)d_out);
}